// Round 4
// baseline (409.474 us; speedup 1.0000x reference)
//
#include <hip/hip_runtime.h>
#include <hip/hip_cooperative_groups.h>
#include <stdint.h>

namespace cg = cooperative_groups;

#define IN_F  32
#define HID_F 64
#define OUT_F 32

#define BKT_SHIFT 8            // 256 nodes per bucket
#define BKT_NODES 256
#define NBLK      512          // partition blocks — count/append edge->block map MUST match

// bf16 helpers (round-to-nearest-even; inputs are finite)
__device__ inline unsigned short f2bf(float f) {
    unsigned u = __float_as_uint(f);
    return (unsigned short)((u + 0x7FFF + ((u >> 16) & 1)) >> 16);
}
// packed-pair unpack: word = (bf16 hi << 16) | bf16 lo ; lo = even feature
__device__ inline float bflo(unsigned w) { return __uint_as_float(w << 16); }
__device__ inline float bfhi(unsigned w) { return __uint_as_float(w & 0xFFFF0000u); }

// NOTE: no non-temporal loads/stores anywhere (R2 lesson: every "stream" here is
// reused; nt killed L2 write-combining/reuse and cost ~50 us total).

// 512-entry exclusive scan in LDS with 256 threads. s[512] in/out, sums[256] scratch.
__device__ inline void scan512_excl(int* s, int* sums, int tid) {
    int a = s[2 * tid], b = s[2 * tid + 1];
    int ts = a + b;
    sums[tid] = ts;
    __syncthreads();
    #pragma unroll
    for (int off = 1; off < 256; off <<= 1) {
        int t = (tid >= off) ? sums[tid - off] : 0;
        __syncthreads();
        sums[tid] += t;
        __syncthreads();
    }
    int texcl = sums[tid] - ts;
    s[2 * tid]     = texcl;
    s[2 * tid + 1] = texcl + a;
    __syncthreads();
}

// ============ fused preprocessing: count -> cellscan -> append -> place+xs ============
// One cooperative kernel replaces count/bsum/bscan/cscan/append/place: kills 5 launch
// boundaries (+ their L2 drains) and keeps each block's dst slice L2-hot from phase A
// into phase C. Co-residency: 512 blocks x 256 thr, ~7 KB LDS, low VGPR -> trivially
// co-resident (capacity ~8 blocks/CU, need 2).
__global__ __launch_bounds__(256) void prep_kernel(
    const int* __restrict__ src, const int* __restrict__ dst,
    int* __restrict__ cnt, int* __restrict__ btot, int* __restrict__ cellx,
    unsigned* __restrict__ pairs, int* __restrict__ srcs,
    int* __restrict__ rowstart, float* __restrict__ dinv,
    const float* __restrict__ x, unsigned* __restrict__ xs2,
    int E, int n, int nb)
{
    __shared__ int sA[1024];   // A: hist | C: cursors | D: hist[0:256]+ofs[256:512]
    __shared__ int sB[512];    // C/D: bucket bases (scanned)
    __shared__ int sS[256];    // scan scratch | D: sdv (as float)
    cg::grid_group grid = cg::this_grid();
    int tid = threadIdx.x, blk = blockIdx.x;

    // ---- phase A: per-(bucket,block) counts ----
    for (int i = tid; i < nb; i += 256) sA[i] = 0;
    __syncthreads();
    for (int e = blk * 256 + tid; e < E; e += NBLK * 256)
        atomicAdd(&sA[dst[e] >> BKT_SHIFT], 1);
    __syncthreads();
    for (int i = tid; i < nb; i += 256) cnt[i * NBLK + blk] = sA[i];

    grid.sync();

    // ---- phase B: per-bucket exclusive scan of its 512 cells + bucket total ----
    if (blk < nb) {
        int c0 = cnt[blk * NBLK + 2 * tid];
        int c1 = cnt[blk * NBLK + 2 * tid + 1];
        int ps = c0 + c1;
        sS[tid] = ps;
        __syncthreads();
        #pragma unroll
        for (int off = 1; off < 256; off <<= 1) {
            int t = (tid >= off) ? sS[tid - off] : 0;
            __syncthreads();
            sS[tid] += t;
            __syncthreads();
        }
        int incl = sS[tid], excl = incl - ps;
        cellx[blk * NBLK + 2 * tid]     = excl;
        cellx[blk * NBLK + 2 * tid + 1] = excl + c0;
        if (tid == 255) btot[blk] = incl;
    }

    grid.sync();

    // ---- phase C: append (dst slice L2-hot from phase A) ----
    // bucket bases: redundant per-block 512-wide scan of btot (~391 ints, cheap)
    sB[tid]       = (tid < nb)       ? btot[tid]       : 0;
    sB[256 + tid] = (256 + tid < nb) ? btot[256 + tid] : 0;
    __syncthreads();
    scan512_excl(sB, sS, tid);                    // sB = exclusive bucket bases
    for (int i = tid; i < nb; i += 256) sA[i] = sB[i] + cellx[i * NBLK + blk];
    __syncthreads();
    for (int e = blk * 256 + tid; e < E; e += NBLK * 256) {
        int d = dst[e];
        int pos = atomicAdd(&sA[d >> BKT_SHIFT], 1);      // LDS atomic
        pairs[pos] = ((unsigned)src[e] << BKT_SHIFT) | (unsigned)(d & (BKT_NODES - 1));
    }

    grid.sync();

    // ---- phase D: per-bucket place + rowstart + dinv + xs fold ----
    if (blk < nb) {
        sB[tid]       = (tid < nb)       ? btot[tid]       : 0;
        sB[256 + tid] = (256 + tid < nb) ? btot[256 + tid] : 0;
        __syncthreads();
        scan512_excl(sB, sS, tid);                // sB = bases; sS free after this
        int beg = sB[blk];
        int end = beg + btot[blk];
        int* hist = sA;
        int* ofs  = sA + 256;
        float* sdv = (float*)sS;

        hist[tid] = 0;
        __syncthreads();
        for (int e = beg + tid; e < end; e += 256)
            atomicAdd(&hist[pairs[e] & (BKT_NODES - 1)], 1);
        __syncthreads();
        int my = hist[tid];
        ofs[tid] = my;
        __syncthreads();
        #pragma unroll
        for (int off = 1; off < 256; off <<= 1) {
            int t = (tid >= off) ? ofs[tid - off] : 0;
            __syncthreads();
            ofs[tid] += t;
            __syncthreads();
        }
        int excl = ofs[tid] - my;
        int node = blk * BKT_NODES + tid;
        float dv = rsqrtf((float)(my + 1));       // +1 self-loop
        sdv[tid] = dv;
        if (node < n) {
            rowstart[node] = beg + excl;
            dinv[node] = dv;
        }
        __syncthreads();
        ofs[tid] = excl;                          // reuse as LDS cursor
        __syncthreads();
        for (int e = beg + tid; e < end; e += 256) {
            unsigned p = pairs[e];
            int dl = p & (BKT_NODES - 1);
            int pos = beg + atomicAdd(&ofs[dl], 1);
            srcs[pos] = (int)(p >> BKT_SHIFT);
        }
        // folded xs: xs2[node][p] = packed bf16(dinv * x[node][2p..2p+1])
        int base = blk * BKT_NODES;
        for (int idx = tid; idx < BKT_NODES * (IN_F / 2); idx += 256) {
            int nl = idx >> 4;
            int p  = idx & 15;
            int nd = base + nl;
            if (nd < n) {
                float2 v = ((const float2*)x)[((size_t)nd << 4) + p];
                float d = sdv[nl];
                unsigned pack = (unsigned)f2bf(v.x * d) | ((unsigned)f2bf(v.y * d) << 16);
                xs2[((size_t)nd << 4) + p] = pack;
            }
        }
        if (blk == 0 && tid == 0) rowstart[n] = E;
    }
}

// ================= fallback chain (used only if cooperative launch fails) =================
__global__ __launch_bounds__(256) void count_kernel(const int* __restrict__ dst,
                                                    int* __restrict__ cnt, int E, int nb)
{
    __shared__ int hist[1024];
    int tid = threadIdx.x;
    for (int i = tid; i < nb; i += 256) hist[i] = 0;
    __syncthreads();
    for (int e = blockIdx.x * 256 + tid; e < E; e += NBLK * 256)
        atomicAdd(&hist[dst[e] >> BKT_SHIFT], 1);
    __syncthreads();
    for (int i = tid; i < nb; i += 256) cnt[i * NBLK + blockIdx.x] = hist[i];
}

__global__ __launch_bounds__(NBLK) void bsum_kernel(const int* __restrict__ cnt,
                                                    int* __restrict__ bsum)
{
    __shared__ int s[NBLK];
    int tid = threadIdx.x, b = blockIdx.x;
    s[tid] = cnt[b * NBLK + tid];
    __syncthreads();
    for (int off = NBLK / 2; off > 0; off >>= 1) {
        if (tid < off) s[tid] += s[tid + off];
        __syncthreads();
    }
    if (tid == 0) bsum[b] = s[0];
}

__global__ __launch_bounds__(512) void bscan_kernel(int* __restrict__ bsum, int nb,
                                                    int* __restrict__ cellstart, int nc,
                                                    int* __restrict__ rowstart, int n, int E)
{
    __shared__ int s[512];
    int tid = threadIdx.x;
    int my = (tid < nb) ? bsum[tid] : 0;
    s[tid] = my;
    __syncthreads();
    for (int off = 1; off < 512; off <<= 1) {
        int t = (tid >= off) ? s[tid - off] : 0;
        __syncthreads();
        s[tid] += t;
        __syncthreads();
    }
    if (tid < nb) bsum[tid] = s[tid] - my;
    if (tid == 0) { cellstart[nc] = E; rowstart[n] = E; }
}

__global__ __launch_bounds__(NBLK) void cscan_kernel(const int* __restrict__ cnt,
                                                     const int* __restrict__ bsum,
                                                     int* __restrict__ cellstart)
{
    __shared__ int s[NBLK];
    int tid = threadIdx.x, b = blockIdx.x;
    int my = cnt[b * NBLK + tid];
    s[tid] = my;
    __syncthreads();
    for (int off = 1; off < NBLK; off <<= 1) {
        int t = (tid >= off) ? s[tid - off] : 0;
        __syncthreads();
        s[tid] += t;
        __syncthreads();
    }
    cellstart[b * NBLK + tid] = bsum[b] + s[tid] - my;
}

__global__ __launch_bounds__(256) void append_kernel(
    const int* __restrict__ src, const int* __restrict__ dst,
    const int* __restrict__ cellstart, unsigned* __restrict__ pairs, int E, int nb)
{
    __shared__ int cur[1024];
    int tid = threadIdx.x;
    for (int i = tid; i < nb; i += 256) cur[i] = cellstart[i * NBLK + blockIdx.x];
    __syncthreads();
    for (int e = blockIdx.x * 256 + tid; e < E; e += NBLK * 256) {
        int d = dst[e];
        int pos = atomicAdd(&cur[d >> BKT_SHIFT], 1);
        pairs[pos] = ((unsigned)src[e] << BKT_SHIFT) | (unsigned)(d & (BKT_NODES - 1));
    }
}

__global__ __launch_bounds__(256) void place_kernel(
    const int* __restrict__ cellstart, const unsigned* __restrict__ pairs,
    int* __restrict__ srcs, int* __restrict__ rowstart, float* __restrict__ dinv,
    const float* __restrict__ x, unsigned* __restrict__ xs2, int n)
{
    __shared__ int hist[BKT_NODES];
    __shared__ int ofs[BKT_NODES];
    __shared__ float sdv[BKT_NODES];
    int b = blockIdx.x, tid = threadIdx.x;
    int beg = cellstart[b * NBLK], end = cellstart[(b + 1) * NBLK];
    hist[tid] = 0;
    __syncthreads();
    for (int e = beg + tid; e < end; e += 256)
        atomicAdd(&hist[pairs[e] & (BKT_NODES - 1)], 1);
    __syncthreads();
    int my = hist[tid];
    ofs[tid] = my;
    __syncthreads();
    for (int off = 1; off < 256; off <<= 1) {
        int t = (tid >= off) ? ofs[tid - off] : 0;
        __syncthreads();
        ofs[tid] += t;
        __syncthreads();
    }
    int excl = ofs[tid] - my;
    int node = b * BKT_NODES + tid;
    float dv = rsqrtf((float)(my + 1));
    sdv[tid] = dv;
    if (node < n) {
        rowstart[node] = beg + excl;
        dinv[node] = dv;
    }
    __syncthreads();
    ofs[tid] = excl;
    __syncthreads();
    for (int e = beg + tid; e < end; e += 256) {
        unsigned p = pairs[e];
        int dl = p & (BKT_NODES - 1);
        int pos = beg + atomicAdd(&ofs[dl], 1);
        srcs[pos] = (int)(p >> BKT_SHIFT);
    }
    int base = b * BKT_NODES;
    for (int idx = tid; idx < BKT_NODES * (IN_F / 2); idx += 256) {
        int nl = idx >> 4;
        int p  = idx & 15;
        int nd = base + nl;
        if (nd < n) {
            float2 v = ((const float2*)x)[((size_t)nd << 4) + p];
            float d = sdv[nl];
            unsigned pack = (unsigned)f2bf(v.x * d) | ((unsigned)f2bf(v.y * d) << 16);
            xs2[((size_t)nd << 4) + p] = pack;
        }
    }
}

// ================= fused1: quarter-wave gather -> MLP -> packed bf16 hs2 =================
// Measured best shape (R0/R3): 256 threads, 16 nodes/block, 8-deep unroll, 64.0 us.
__global__ __launch_bounds__(256) void fused1_kernel(
    const int* __restrict__ rowstart, const int* __restrict__ srcs,
    const unsigned* __restrict__ xs2, const float* __restrict__ dinv,
    const float* __restrict__ b1, const float* __restrict__ W1,
    const float* __restrict__ W2, unsigned* __restrict__ hs2p, int n)
{
    __shared__ float W1s[IN_F * HID_F];    // 8 KB  [k*64+j]
    __shared__ float W2s[HID_F * OUT_F];   // 8 KB  [k*32+j]
    __shared__ float grow[16][IN_F + 1];   // padded: bank = (nl+k)%32
    __shared__ float hrow[16][HID_F + 1];  // padded
    int tid = threadIdx.x;
    for (int t = tid; t < IN_F * HID_F; t += 256) W1s[t] = W1[t];
    for (int t = tid; t < HID_F * OUT_F; t += 256) W2s[t] = W2[t];

    int nl = tid >> 4;                 // node-local 0..15
    unsigned q = tid & 15;             // feature-pair index
    int node = blockIdx.x * 16 + nl;
    bool active = node < n;
    int nodec = active ? node : 0;

    int beg = rowstart[nodec], end = active ? rowstart[nodec + 1] : beg;
    unsigned ws = active ? xs2[((unsigned)nodec << 4) + q] : 0u;   // self-loop
    float a0l = bflo(ws), a0h = bfhi(ws);
    float a1l = 0.f, a1h = 0.f, a2l = 0.f, a2h = 0.f, a3l = 0.f, a3h = 0.f;
    float a4l = 0.f, a4h = 0.f, a5l = 0.f, a5h = 0.f, a6l = 0.f, a6h = 0.f;
    float a7l = 0.f, a7h = 0.f;
    int e = beg;
    for (; e + 8 <= end; e += 8) {
        unsigned o0 = ((unsigned)srcs[e]     << 4) + q, o1 = ((unsigned)srcs[e + 1] << 4) + q;
        unsigned o2 = ((unsigned)srcs[e + 2] << 4) + q, o3 = ((unsigned)srcs[e + 3] << 4) + q;
        unsigned o4 = ((unsigned)srcs[e + 4] << 4) + q, o5 = ((unsigned)srcs[e + 5] << 4) + q;
        unsigned o6 = ((unsigned)srcs[e + 6] << 4) + q, o7 = ((unsigned)srcs[e + 7] << 4) + q;
        unsigned w0 = xs2[o0], w1 = xs2[o1], w2 = xs2[o2], w3 = xs2[o3];
        unsigned w4 = xs2[o4], w5 = xs2[o5], w6 = xs2[o6], w7 = xs2[o7];
        a0l += bflo(w0); a0h += bfhi(w0); a1l += bflo(w1); a1h += bfhi(w1);
        a2l += bflo(w2); a2h += bfhi(w2); a3l += bflo(w3); a3h += bfhi(w3);
        a4l += bflo(w4); a4h += bfhi(w4); a5l += bflo(w5); a5h += bfhi(w5);
        a6l += bflo(w6); a6h += bfhi(w6); a7l += bflo(w7); a7h += bfhi(w7);
    }
    for (; e + 4 <= end; e += 4) {
        unsigned o0 = ((unsigned)srcs[e]     << 4) + q, o1 = ((unsigned)srcs[e + 1] << 4) + q;
        unsigned o2 = ((unsigned)srcs[e + 2] << 4) + q, o3 = ((unsigned)srcs[e + 3] << 4) + q;
        unsigned w0 = xs2[o0], w1 = xs2[o1], w2 = xs2[o2], w3 = xs2[o3];
        a0l += bflo(w0); a0h += bfhi(w0); a1l += bflo(w1); a1h += bfhi(w1);
        a2l += bflo(w2); a2h += bfhi(w2); a3l += bflo(w3); a3h += bfhi(w3);
    }
    for (; e < end; ++e) {
        unsigned w0 = xs2[((unsigned)srcs[e] << 4) + q];
        a0l += bflo(w0); a0h += bfhi(w0);
    }
    float dv = dinv[nodec];
    grow[nl][2 * q]     = dv * (((a0l + a1l) + (a2l + a3l)) + ((a4l + a5l) + (a6l + a7l)));
    grow[nl][2 * q + 1] = dv * (((a0h + a1h) + (a2h + a3h)) + ((a4h + a5h) + (a6h + a7h)));
    __syncthreads();

    float h0 = b1[q], h1 = b1[q + 16], h2 = b1[q + 32], h3 = b1[q + 48];
    #pragma unroll
    for (int k = 0; k < IN_F; ++k) {
        float gk = grow[nl][k];
        h0 += gk * W1s[k * HID_F + q];
        h1 += gk * W1s[k * HID_F + q + 16];
        h2 += gk * W1s[k * HID_F + q + 32];
        h3 += gk * W1s[k * HID_F + q + 48];
    }
    hrow[nl][q]      = fmaxf(h0, 0.f);
    hrow[nl][q + 16] = fmaxf(h1, 0.f);
    hrow[nl][q + 32] = fmaxf(h2, 0.f);
    hrow[nl][q + 48] = fmaxf(h3, 0.f);
    __syncthreads();

    float p0 = 0.f, p1 = 0.f;
    #pragma unroll
    for (int k = 0; k < HID_F; ++k) {
        float hk = hrow[nl][k];
        p0 += hk * W2s[k * OUT_F + 2 * q];
        p1 += hk * W2s[k * OUT_F + 2 * q + 1];
    }
    if (active) {
        unsigned pack = (unsigned)f2bf(dv * p0) | ((unsigned)f2bf(dv * p1) << 16);
        hs2p[((unsigned)node << 4) + q] = pack;
    }
}

// ================= agg2: eighth-wave gather of packed hs2 (uint2), finalize =================
__global__ __launch_bounds__(256) void agg2_kernel(
    const int* __restrict__ rowstart, const int* __restrict__ srcs,
    const uint2* __restrict__ hs2p2, const float* __restrict__ dinv,
    const float* __restrict__ b2, float* __restrict__ out, int n)
{
    int t = blockIdx.x * blockDim.x + threadIdx.x;
    int node = t >> 3;
    if (node >= n) return;
    unsigned r = t & 7;
    int beg = rowstart[node], end = rowstart[node + 1];
    uint2 ws = hs2p2[((unsigned)node << 3) + r];     // self-loop
    float a0x = bflo(ws.x), a0y = bfhi(ws.x), a0z = bflo(ws.y), a0w = bfhi(ws.y);
    float a1x = 0.f, a1y = 0.f, a1z = 0.f, a1w = 0.f;
    float a2x = 0.f, a2y = 0.f, a2z = 0.f, a2w = 0.f;
    float a3x = 0.f, a3y = 0.f, a3z = 0.f, a3w = 0.f;
    int e = beg;
    for (; e + 4 <= end; e += 4) {
        unsigned o0 = ((unsigned)srcs[e]     << 3) + r, o1 = ((unsigned)srcs[e + 1] << 3) + r;
        unsigned o2 = ((unsigned)srcs[e + 2] << 3) + r, o3 = ((unsigned)srcs[e + 3] << 3) + r;
        uint2 w0 = hs2p2[o0], w1 = hs2p2[o1], w2 = hs2p2[o2], w3 = hs2p2[o3];
        a0x += bflo(w0.x); a0y += bfhi(w0.x); a0z += bflo(w0.y); a0w += bfhi(w0.y);
        a1x += bflo(w1.x); a1y += bfhi(w1.x); a1z += bflo(w1.y); a1w += bfhi(w1.y);
        a2x += bflo(w2.x); a2y += bfhi(w2.x); a2z += bflo(w2.y); a2w += bfhi(w2.y);
        a3x += bflo(w3.x); a3y += bfhi(w3.x); a3z += bflo(w3.y); a3w += bfhi(w3.y);
    }
    for (; e < end; ++e) {
        uint2 w0 = hs2p2[((unsigned)srcs[e] << 3) + r];
        a0x += bflo(w0.x); a0y += bfhi(w0.x); a0z += bflo(w0.y); a0w += bfhi(w0.y);
    }
    float dvv = dinv[node];
    float4 bb = ((const float4*)b2)[r];
    float4 res;
    res.x = dvv * ((a0x + a1x) + (a2x + a3x)) + bb.x;
    res.y = dvv * ((a0y + a1y) + (a2y + a3y)) + bb.y;
    res.z = dvv * ((a0z + a1z) + (a2z + a3z)) + bb.z;
    res.w = dvv * ((a0w + a1w) + (a2w + a3w)) + bb.w;
    ((float4*)out)[((size_t)node << 3) + r] = res;
}

extern "C" void kernel_launch(void* const* d_in, const int* in_sizes, int n_in,
                              void* d_out, int out_size, void* d_ws, size_t ws_size,
                              hipStream_t stream) {
    const float* x  = (const float*)d_in[0];
    const int*   ei = (const int*)  d_in[1];
    const float* W1 = (const float*)d_in[2];
    const float* b1 = (const float*)d_in[3];
    const float* W2 = (const float*)d_in[4];
    const float* b2 = (const float*)d_in[5];
    float* out = (float*)d_out;

    int n = in_sizes[0] / IN_F;     // 100000
    int E = in_sizes[1] / 2;        // 1600000
    const int* src = ei;
    const int* dst = ei + E;

    int nb = (n + BKT_NODES - 1) >> BKT_SHIFT;   // 391 buckets (<=512)
    const int nc = nb * NBLK;                    // 200192 cells

    // ---- workspace layout: ~27 MB (16 B aligned regions for vector access) ----
    auto align16 = [](int* p) { return (int*)(((uintptr_t)p + 15) & ~(uintptr_t)15); };
    int* ip = (int*)d_ws;
    int* cnt       = ip;                 ip += nc;         // 0.8 MB
    int* cellx     = ip;                 ip += nc + 1;     // 0.8 MB (within-bucket excl. cell scan)
    int* btot      = ip;                 ip += nb + 1;     // bucket totals / bases (fallback)
    int* rowstart  = ip;                 ip += n + 1;
    ip = align16(ip);
    unsigned* pairs = (unsigned*)ip;     ip += E;          // 6.4 MB
    int* srcs_srt  = ip;                 ip += E;          // 6.4 MB
    float* dinv = (float*)ip;            ip += n;
    ip = align16(ip);
    unsigned* xs2  = (unsigned*)ip;      ip += (size_t)n * IN_F / 2;   // 6.4 MB
    ip = align16(ip);
    unsigned* hs2p = (unsigned*)ip;                                    // 6.4 MB

    // ---- fused cooperative preprocessing (fallback: proven 6-kernel chain) ----
    void* kargs[] = { (void*)&src, (void*)&dst, (void*)&cnt, (void*)&btot, (void*)&cellx,
                      (void*)&pairs, (void*)&srcs_srt, (void*)&rowstart, (void*)&dinv,
                      (void*)&x, (void*)&xs2, (void*)&E, (void*)&n, (void*)&nb };
    hipError_t ce = hipLaunchCooperativeKernel((void*)prep_kernel, dim3(NBLK), dim3(256),
                                               kargs, 0, stream);
    if (ce != hipSuccess) {
        (void)hipGetLastError();   // clear sticky error, use fallback chain
        count_kernel<<<NBLK, 256, 0, stream>>>(dst, cnt, E, nb);
        bsum_kernel <<<nb, NBLK, 0, stream>>>(cnt, btot);
        bscan_kernel<<<1, 512, 0, stream>>>(btot, nb, cellx, nc, rowstart, n, E);
        cscan_kernel<<<nb, NBLK, 0, stream>>>(cnt, btot, cellx);
        append_kernel<<<NBLK, 256, 0, stream>>>(src, dst, cellx, pairs, E, nb);
        place_kernel<<<nb, 256, 0, stream>>>(cellx, pairs, srcs_srt, rowstart, dinv, x, xs2, n);
    }

    fused1_kernel<<<(n + 15) / 16, 256, 0, stream>>>(rowstart, srcs_srt, xs2, dinv, b1, W1, W2, hs2p, n);
    agg2_kernel<<<((size_t)n * 8 + 255) / 256, 256, 0, stream>>>(rowstart, srcs_srt, (const uint2*)hs2p, dinv, b2, out, n);
}

// Round 5
// 230.079 us; speedup vs baseline: 1.7797x; 1.7797x over previous
//
#include <hip/hip_runtime.h>
#include <stdint.h>

#define IN_F  32
#define HID_F 64
#define OUT_F 32

#define BKT_SHIFT 8            // 256 nodes per bucket
#define BKT_NODES 256
#define NBLK      512          // partition blocks — count/append edge->block map MUST match

// bf16 helpers (round-to-nearest-even; inputs are finite)
__device__ inline unsigned short f2bf(float f) {
    unsigned u = __float_as_uint(f);
    return (unsigned short)((u + 0x7FFF + ((u >> 16) & 1)) >> 16);
}
// packed-pair unpack: word = (bf16 hi << 16) | bf16 lo ; lo = even feature
__device__ inline float bflo(unsigned w) { return __uint_as_float(w << 16); }
__device__ inline float bfhi(unsigned w) { return __uint_as_float(w & 0xFFFF0000u); }

// R2 lesson: no non-temporal loads/stores (every "stream" here is reused; nt cost ~50us).
// R4 lesson: no cooperative grid.sync on this chip (~45us per sync; 2.5x regression).
// Launch boundaries in graph capture are cheap (~2-3us) — prefer the kernel chain.

// ================= phase 1: per-(bucket,block) exact counts + bucket totals =================
// btot must be zeroed before launch (hipMemsetAsync, 1.5KB). Folds old bsum_kernel:
// the per-block LDS histogram is atomically accumulated into global btot (391 counters
// x 512 adds, device-scope, low contention).
__global__ __launch_bounds__(256) void count_kernel(const int* __restrict__ dst,
                                                    int* __restrict__ cnt,
                                                    int* __restrict__ btot, int E, int nb)
{
    __shared__ int hist[1024];          // nb <= 1024
    int tid = threadIdx.x;
    for (int i = tid; i < nb; i += 256) hist[i] = 0;
    __syncthreads();
    for (int e = blockIdx.x * 256 + tid; e < E; e += NBLK * 256)
        atomicAdd(&hist[dst[e] >> BKT_SHIFT], 1);
    __syncthreads();
    for (int i = tid; i < nb; i += 256) {
        int h = hist[i];
        cnt[i * NBLK + blockIdx.x] = h;
        if (h) atomicAdd(&btot[i], h);
    }
}

// ================= phase 2: per-bucket cell scan (+ folded bucket-base scan) =================
// Folds old bscan_kernel: every block redundantly scans btot (<=512 ints) in LDS and
// extracts its own bucket base — removes the serial 1-block bscan launch.
__global__ __launch_bounds__(NBLK) void cscan_kernel(const int* __restrict__ cnt,
                                                     const int* __restrict__ btot,
                                                     int* __restrict__ cellstart,
                                                     int nb, int nc, int E)
{
    __shared__ int s[NBLK];
    __shared__ int sbase;
    int tid = threadIdx.x, b = blockIdx.x;
    // ---- bucket base: exclusive prefix of btot[0..b) ----
    int bv = (tid < nb) ? btot[tid] : 0;
    s[tid] = bv;
    __syncthreads();
    for (int off = 1; off < NBLK; off <<= 1) {
        int t = (tid >= off) ? s[tid - off] : 0;
        __syncthreads();
        s[tid] += t;
        __syncthreads();
    }
    if (tid == b) sbase = s[tid] - bv;     // exclusive base of bucket b (b < nb <= NBLK)
    __syncthreads();
    int base = sbase;
    // ---- within-bucket scan of its NBLK cells ----
    int my = cnt[b * NBLK + tid];
    s[tid] = my;
    __syncthreads();
    for (int off = 1; off < NBLK; off <<= 1) {
        int t = (tid >= off) ? s[tid - off] : 0;
        __syncthreads();
        s[tid] += t;
        __syncthreads();
    }
    cellstart[b * NBLK + tid] = base + s[tid] - my;   // exclusive
    if (b == 0 && tid == 0) cellstart[nc] = E;
}

// ================= phase 3: append via block-private LDS cursors =================
__global__ __launch_bounds__(256) void append_kernel(
    const int* __restrict__ src, const int* __restrict__ dst,
    const int* __restrict__ cellstart, unsigned* __restrict__ pairs, int E, int nb)
{
    __shared__ int cur[1024];
    int tid = threadIdx.x;
    for (int i = tid; i < nb; i += 256) cur[i] = cellstart[i * NBLK + blockIdx.x];
    __syncthreads();
    for (int e = blockIdx.x * 256 + tid; e < E; e += NBLK * 256) {
        int d = dst[e];
        int pos = atomicAdd(&cur[d >> BKT_SHIFT], 1);     // LDS atomic
        pairs[pos] = ((unsigned)src[e] << BKT_SHIFT) | (unsigned)(d & (BKT_NODES - 1));
    }
}

// ================= phase 4: per-bucket place + rowstart + dinv + xs (folded) =================
__global__ __launch_bounds__(256) void place_kernel(
    const int* __restrict__ cellstart, const unsigned* __restrict__ pairs,
    int* __restrict__ srcs, int* __restrict__ rowstart, float* __restrict__ dinv,
    const float* __restrict__ x, unsigned* __restrict__ xs2, int n, int E)
{
    __shared__ int hist[BKT_NODES];
    __shared__ int ofs[BKT_NODES];
    __shared__ float sdv[BKT_NODES];
    int b = blockIdx.x, tid = threadIdx.x;
    int beg = cellstart[b * NBLK], end = cellstart[(b + 1) * NBLK];
    hist[tid] = 0;
    __syncthreads();
    for (int e = beg + tid; e < end; e += 256)
        atomicAdd(&hist[pairs[e] & (BKT_NODES - 1)], 1);
    __syncthreads();
    int my = hist[tid];
    ofs[tid] = my;
    __syncthreads();
    for (int off = 1; off < 256; off <<= 1) {
        int t = (tid >= off) ? ofs[tid - off] : 0;
        __syncthreads();
        ofs[tid] += t;
        __syncthreads();
    }
    int excl = ofs[tid] - my;
    int node = b * BKT_NODES + tid;
    float dv = rsqrtf((float)(my + 1));     // +1 self-loop
    sdv[tid] = dv;
    if (node < n) {
        rowstart[node] = beg + excl;
        dinv[node] = dv;
    }
    if (b == 0 && tid == 0) rowstart[n] = E;
    __syncthreads();
    ofs[tid] = excl;                    // reuse as LDS cursor
    __syncthreads();
    for (int e = beg + tid; e < end; e += 256) {
        unsigned p = pairs[e];
        int dl = p & (BKT_NODES - 1);
        int pos = beg + atomicAdd(&ofs[dl], 1);
        srcs[pos] = (int)(p >> BKT_SHIFT);
    }
    // ---- folded xs: xs2[node][p] = packed bf16(dinv * x[node][2p..2p+1]) ----
    int base = b * BKT_NODES;
    for (int idx = tid; idx < BKT_NODES * (IN_F / 2); idx += 256) {
        int nl = idx >> 4;
        int p  = idx & 15;
        int nd = base + nl;
        if (nd < n) {
            float2 v = ((const float2*)x)[((size_t)nd << 4) + p];
            float d = sdv[nl];
            unsigned pack = (unsigned)f2bf(v.x * d) | ((unsigned)f2bf(v.y * d) << 16);
            xs2[((size_t)nd << 4) + p] = pack;
        }
    }
}

// ================= fused1: quarter-wave gather -> MLP -> packed bf16 hs2 =================
// Measured best shape (R0/R3): 256 threads, 16 nodes/block, 8-deep unroll, 64.0 us.
__global__ __launch_bounds__(256) void fused1_kernel(
    const int* __restrict__ rowstart, const int* __restrict__ srcs,
    const unsigned* __restrict__ xs2, const float* __restrict__ dinv,
    const float* __restrict__ b1, const float* __restrict__ W1,
    const float* __restrict__ W2, unsigned* __restrict__ hs2p, int n)
{
    __shared__ float W1s[IN_F * HID_F];    // 8 KB  [k*64+j]
    __shared__ float W2s[HID_F * OUT_F];   // 8 KB  [k*32+j]
    __shared__ float grow[16][IN_F + 1];   // padded: bank = (nl+k)%32
    __shared__ float hrow[16][HID_F + 1];  // padded
    int tid = threadIdx.x;
    for (int t = tid; t < IN_F * HID_F; t += 256) W1s[t] = W1[t];
    for (int t = tid; t < HID_F * OUT_F; t += 256) W2s[t] = W2[t];

    int nl = tid >> 4;                 // node-local 0..15
    unsigned q = tid & 15;             // feature-pair index
    int node = blockIdx.x * 16 + nl;
    bool active = node < n;
    int nodec = active ? node : 0;

    int beg = rowstart[nodec], end = active ? rowstart[nodec + 1] : beg;
    unsigned ws = active ? xs2[((unsigned)nodec << 4) + q] : 0u;   // self-loop
    float a0l = bflo(ws), a0h = bfhi(ws);
    float a1l = 0.f, a1h = 0.f, a2l = 0.f, a2h = 0.f, a3l = 0.f, a3h = 0.f;
    float a4l = 0.f, a4h = 0.f, a5l = 0.f, a5h = 0.f, a6l = 0.f, a6h = 0.f;
    float a7l = 0.f, a7h = 0.f;
    int e = beg;
    for (; e + 8 <= end; e += 8) {
        unsigned o0 = ((unsigned)srcs[e]     << 4) + q, o1 = ((unsigned)srcs[e + 1] << 4) + q;
        unsigned o2 = ((unsigned)srcs[e + 2] << 4) + q, o3 = ((unsigned)srcs[e + 3] << 4) + q;
        unsigned o4 = ((unsigned)srcs[e + 4] << 4) + q, o5 = ((unsigned)srcs[e + 5] << 4) + q;
        unsigned o6 = ((unsigned)srcs[e + 6] << 4) + q, o7 = ((unsigned)srcs[e + 7] << 4) + q;
        unsigned w0 = xs2[o0], w1 = xs2[o1], w2 = xs2[o2], w3 = xs2[o3];
        unsigned w4 = xs2[o4], w5 = xs2[o5], w6 = xs2[o6], w7 = xs2[o7];
        a0l += bflo(w0); a0h += bfhi(w0); a1l += bflo(w1); a1h += bfhi(w1);
        a2l += bflo(w2); a2h += bfhi(w2); a3l += bflo(w3); a3h += bfhi(w3);
        a4l += bflo(w4); a4h += bfhi(w4); a5l += bflo(w5); a5h += bfhi(w5);
        a6l += bflo(w6); a6h += bfhi(w6); a7l += bflo(w7); a7h += bfhi(w7);
    }
    for (; e + 4 <= end; e += 4) {
        unsigned o0 = ((unsigned)srcs[e]     << 4) + q, o1 = ((unsigned)srcs[e + 1] << 4) + q;
        unsigned o2 = ((unsigned)srcs[e + 2] << 4) + q, o3 = ((unsigned)srcs[e + 3] << 4) + q;
        unsigned w0 = xs2[o0], w1 = xs2[o1], w2 = xs2[o2], w3 = xs2[o3];
        a0l += bflo(w0); a0h += bfhi(w0); a1l += bflo(w1); a1h += bfhi(w1);
        a2l += bflo(w2); a2h += bfhi(w2); a3l += bflo(w3); a3h += bfhi(w3);
    }
    for (; e < end; ++e) {
        unsigned w0 = xs2[((unsigned)srcs[e] << 4) + q];
        a0l += bflo(w0); a0h += bfhi(w0);
    }
    float dv = dinv[nodec];
    grow[nl][2 * q]     = dv * (((a0l + a1l) + (a2l + a3l)) + ((a4l + a5l) + (a6l + a7l)));
    grow[nl][2 * q + 1] = dv * (((a0h + a1h) + (a2h + a3h)) + ((a4h + a5h) + (a6h + a7h)));
    __syncthreads();

    // ---- MLP: 16 threads/node. hidden features q, q+16, q+32, q+48 ----
    float h0 = b1[q], h1 = b1[q + 16], h2 = b1[q + 32], h3 = b1[q + 48];
    #pragma unroll
    for (int k = 0; k < IN_F; ++k) {
        float gk = grow[nl][k];
        h0 += gk * W1s[k * HID_F + q];
        h1 += gk * W1s[k * HID_F + q + 16];
        h2 += gk * W1s[k * HID_F + q + 32];
        h3 += gk * W1s[k * HID_F + q + 48];
    }
    hrow[nl][q]      = fmaxf(h0, 0.f);
    hrow[nl][q + 16] = fmaxf(h1, 0.f);
    hrow[nl][q + 32] = fmaxf(h2, 0.f);
    hrow[nl][q + 48] = fmaxf(h3, 0.f);
    __syncthreads();

    // ---- W2 matvec: output features 2q, 2q+1; write packed pair ----
    float p0 = 0.f, p1 = 0.f;
    #pragma unroll
    for (int k = 0; k < HID_F; ++k) {
        float hk = hrow[nl][k];
        p0 += hk * W2s[k * OUT_F + 2 * q];
        p1 += hk * W2s[k * OUT_F + 2 * q + 1];
    }
    if (active) {
        unsigned pack = (unsigned)f2bf(dv * p0) | ((unsigned)f2bf(dv * p1) << 16);
        hs2p[((unsigned)node << 4) + q] = pack;
    }
}

// ================= agg2: eighth-wave gather of packed hs2 (uint2), finalize =================
__global__ __launch_bounds__(256) void agg2_kernel(
    const int* __restrict__ rowstart, const int* __restrict__ srcs,
    const uint2* __restrict__ hs2p2, const float* __restrict__ dinv,
    const float* __restrict__ b2, float* __restrict__ out, int n)
{
    int t = blockIdx.x * blockDim.x + threadIdx.x;
    int node = t >> 3;
    if (node >= n) return;
    unsigned r = t & 7;
    int beg = rowstart[node], end = rowstart[node + 1];
    uint2 ws = hs2p2[((unsigned)node << 3) + r];     // self-loop
    float a0x = bflo(ws.x), a0y = bfhi(ws.x), a0z = bflo(ws.y), a0w = bfhi(ws.y);
    float a1x = 0.f, a1y = 0.f, a1z = 0.f, a1w = 0.f;
    float a2x = 0.f, a2y = 0.f, a2z = 0.f, a2w = 0.f;
    float a3x = 0.f, a3y = 0.f, a3z = 0.f, a3w = 0.f;
    int e = beg;
    for (; e + 4 <= end; e += 4) {
        unsigned o0 = ((unsigned)srcs[e]     << 3) + r, o1 = ((unsigned)srcs[e + 1] << 3) + r;
        unsigned o2 = ((unsigned)srcs[e + 2] << 3) + r, o3 = ((unsigned)srcs[e + 3] << 3) + r;
        uint2 w0 = hs2p2[o0], w1 = hs2p2[o1], w2 = hs2p2[o2], w3 = hs2p2[o3];
        a0x += bflo(w0.x); a0y += bfhi(w0.x); a0z += bflo(w0.y); a0w += bfhi(w0.y);
        a1x += bflo(w1.x); a1y += bfhi(w1.x); a1z += bflo(w1.y); a1w += bfhi(w1.y);
        a2x += bflo(w2.x); a2y += bfhi(w2.x); a2z += bflo(w2.y); a2w += bfhi(w2.y);
        a3x += bflo(w3.x); a3y += bfhi(w3.x); a3z += bflo(w3.y); a3w += bfhi(w3.y);
    }
    for (; e < end; ++e) {
        uint2 w0 = hs2p2[((unsigned)srcs[e] << 3) + r];
        a0x += bflo(w0.x); a0y += bfhi(w0.x); a0z += bflo(w0.y); a0w += bfhi(w0.y);
    }
    float dvv = dinv[node];
    float4 bb = ((const float4*)b2)[r];
    float4 res;
    res.x = dvv * ((a0x + a1x) + (a2x + a3x)) + bb.x;
    res.y = dvv * ((a0y + a1y) + (a2y + a3y)) + bb.y;
    res.z = dvv * ((a0z + a1z) + (a2z + a3z)) + bb.z;
    res.w = dvv * ((a0w + a1w) + (a2w + a3w)) + bb.w;
    ((float4*)out)[((size_t)node << 3) + r] = res;
}

extern "C" void kernel_launch(void* const* d_in, const int* in_sizes, int n_in,
                              void* d_out, int out_size, void* d_ws, size_t ws_size,
                              hipStream_t stream) {
    const float* x  = (const float*)d_in[0];
    const int*   ei = (const int*)  d_in[1];
    const float* W1 = (const float*)d_in[2];
    const float* b1 = (const float*)d_in[3];
    const float* W2 = (const float*)d_in[4];
    const float* b2 = (const float*)d_in[5];
    float* out = (float*)d_out;

    const int n = in_sizes[0] / IN_F;     // 100000
    const int E = in_sizes[1] / 2;        // 1600000
    const int* src = ei;
    const int* dst = ei + E;

    const int nb = (n + BKT_NODES - 1) >> BKT_SHIFT;   // 391 buckets (<=512)
    const int nc = nb * NBLK;                          // 200192 cells

    // ---- workspace layout: ~27 MB (16 B aligned regions for vector access) ----
    auto align16 = [](int* p) { return (int*)(((uintptr_t)p + 15) & ~(uintptr_t)15); };
    int* ip = (int*)d_ws;
    int* cnt       = ip;                 ip += nc;         // 0.8 MB
    int* cellstart = ip;                 ip += nc + 1;     // 0.8 MB
    int* btot      = ip;                 ip += nb + 1;     // bucket totals (atomic-accumulated)
    int* rowstart  = ip;                 ip += n + 1;
    ip = align16(ip);
    unsigned* pairs = (unsigned*)ip;     ip += E;          // 6.4 MB
    int* srcs_srt  = ip;                 ip += E;          // 6.4 MB
    float* dinv = (float*)ip;            ip += n;
    ip = align16(ip);
    unsigned* xs2  = (unsigned*)ip;      ip += (size_t)n * IN_F / 2;   // 6.4 MB
    ip = align16(ip);
    unsigned* hs2p = (unsigned*)ip;                                    // 6.4 MB

    hipMemsetAsync(btot, 0, (nb + 1) * sizeof(int), stream);
    count_kernel<<<NBLK, 256, 0, stream>>>(dst, cnt, btot, E, nb);
    cscan_kernel<<<nb, NBLK, 0, stream>>>(cnt, btot, cellstart, nb, nc, E);
    append_kernel<<<NBLK, 256, 0, stream>>>(src, dst, cellstart, pairs, E, nb);
    place_kernel<<<nb, 256, 0, stream>>>(cellstart, pairs, srcs_srt, rowstart, dinv, x, xs2, n, E);

    fused1_kernel<<<(n + 15) / 16, 256, 0, stream>>>(rowstart, srcs_srt, xs2, dinv, b1, W1, W2, hs2p, n);
    agg2_kernel<<<((size_t)n * 8 + 255) / 256, 256, 0, stream>>>(rowstart, srcs_srt, (const uint2*)hs2p, dinv, b2, out, n);
}

// Round 6
// 212.022 us; speedup vs baseline: 1.9313x; 1.0852x over previous
//
#include <hip/hip_runtime.h>
#include <stdint.h>

#define IN_F  32
#define HID_F 64
#define OUT_F 32

#define BKT_SHIFT 8            // 256 nodes per bucket
#define BKT_NODES 256
#define NBLK      512          // partition blocks — count/append edge->block map MUST match

// bf16 helpers (round-to-nearest-even; inputs are finite)
__device__ inline unsigned short f2bf(float f) {
    unsigned u = __float_as_uint(f);
    return (unsigned short)((u + 0x7FFF + ((u >> 16) & 1)) >> 16);
}
// packed-pair unpack: word = (bf16 hi << 16) | bf16 lo ; lo = even feature
__device__ inline float bflo(unsigned w) { return __uint_as_float(w << 16); }
__device__ inline float bfhi(unsigned w) { return __uint_as_float(w & 0xFFFF0000u); }

// Ledger: R2 no-nt (reused streams; −50us), R4 no grid.sync (~45us/sync),
// R5 no atomic/scan folds (+16us). R3 chain below is the measured optimum.

// ================= phase 1: per-(bucket,block) exact counts =================
__global__ __launch_bounds__(256) void count_kernel(const int* __restrict__ dst,
                                                    int* __restrict__ cnt, int E, int nb)
{
    __shared__ int hist[1024];          // nb <= 1024
    int tid = threadIdx.x;
    for (int i = tid; i < nb; i += 256) hist[i] = 0;
    __syncthreads();
    for (int e = blockIdx.x * 256 + tid; e < E; e += NBLK * 256)
        atomicAdd(&hist[dst[e] >> BKT_SHIFT], 1);
    __syncthreads();
    for (int i = tid; i < nb; i += 256) cnt[i * NBLK + blockIdx.x] = hist[i];
}

// ================= phase 2a: per-bucket totals (one block per bucket) =================
__global__ __launch_bounds__(NBLK) void bsum_kernel(const int* __restrict__ cnt,
                                                    int* __restrict__ bsum)
{
    __shared__ int s[NBLK];
    int tid = threadIdx.x, b = blockIdx.x;
    s[tid] = cnt[b * NBLK + tid];
    __syncthreads();
    for (int off = NBLK / 2; off > 0; off >>= 1) {
        if (tid < off) s[tid] += s[tid + off];
        __syncthreads();
    }
    if (tid == 0) bsum[b] = s[0];
}

// ================= phase 2b: one-block exclusive scan of bucket totals =================
__global__ __launch_bounds__(512) void bscan_kernel(int* __restrict__ bsum, int nb,
                                                    int* __restrict__ cellstart, int nc,
                                                    int* __restrict__ rowstart, int n, int E)
{
    __shared__ int s[512];
    int tid = threadIdx.x;
    int my = (tid < nb) ? bsum[tid] : 0;
    s[tid] = my;
    __syncthreads();
    for (int off = 1; off < 512; off <<= 1) {
        int t = (tid >= off) ? s[tid - off] : 0;
        __syncthreads();
        s[tid] += t;
        __syncthreads();
    }
    if (tid < nb) bsum[tid] = s[tid] - my;      // exclusive bucket start
    if (tid == 0) { cellstart[nc] = E; rowstart[n] = E; }
}

// ================= phase 2c: per-bucket scan of its NBLK cells =================
__global__ __launch_bounds__(NBLK) void cscan_kernel(const int* __restrict__ cnt,
                                                     const int* __restrict__ bsum,
                                                     int* __restrict__ cellstart)
{
    __shared__ int s[NBLK];
    int tid = threadIdx.x, b = blockIdx.x;
    int my = cnt[b * NBLK + tid];
    s[tid] = my;
    __syncthreads();
    for (int off = 1; off < NBLK; off <<= 1) {
        int t = (tid >= off) ? s[tid - off] : 0;
        __syncthreads();
        s[tid] += t;
        __syncthreads();
    }
    cellstart[b * NBLK + tid] = bsum[b] + s[tid] - my;   // exclusive
}

// ================= phase 3: append via block-private LDS cursors =================
__global__ __launch_bounds__(256) void append_kernel(
    const int* __restrict__ src, const int* __restrict__ dst,
    const int* __restrict__ cellstart, unsigned* __restrict__ pairs, int E, int nb)
{
    __shared__ int cur[1024];
    int tid = threadIdx.x;
    for (int i = tid; i < nb; i += 256) cur[i] = cellstart[i * NBLK + blockIdx.x];
    __syncthreads();
    for (int e = blockIdx.x * 256 + tid; e < E; e += NBLK * 256) {
        int d = dst[e];
        int pos = atomicAdd(&cur[d >> BKT_SHIFT], 1);     // LDS atomic
        pairs[pos] = ((unsigned)src[e] << BKT_SHIFT) | (unsigned)(d & (BKT_NODES - 1));
    }
}

// ================= phase 4: per-bucket place + rowstart + dinv + xs (folded) =================
__global__ __launch_bounds__(256) void place_kernel(
    const int* __restrict__ cellstart, const unsigned* __restrict__ pairs,
    int* __restrict__ srcs, int* __restrict__ rowstart, float* __restrict__ dinv,
    const float* __restrict__ x, unsigned* __restrict__ xs2, int n)
{
    __shared__ int hist[BKT_NODES];
    __shared__ int ofs[BKT_NODES];
    __shared__ float sdv[BKT_NODES];
    int b = blockIdx.x, tid = threadIdx.x;
    int beg = cellstart[b * NBLK], end = cellstart[(b + 1) * NBLK];
    hist[tid] = 0;
    __syncthreads();
    for (int e = beg + tid; e < end; e += 256)
        atomicAdd(&hist[pairs[e] & (BKT_NODES - 1)], 1);
    __syncthreads();
    int my = hist[tid];
    ofs[tid] = my;
    __syncthreads();
    for (int off = 1; off < 256; off <<= 1) {
        int t = (tid >= off) ? ofs[tid - off] : 0;
        __syncthreads();
        ofs[tid] += t;
        __syncthreads();
    }
    int excl = ofs[tid] - my;
    int node = b * BKT_NODES + tid;
    float dv = rsqrtf((float)(my + 1));     // +1 self-loop
    sdv[tid] = dv;
    if (node < n) {
        rowstart[node] = beg + excl;
        dinv[node] = dv;
    }
    __syncthreads();
    ofs[tid] = excl;                    // reuse as LDS cursor
    __syncthreads();
    for (int e = beg + tid; e < end; e += 256) {
        unsigned p = pairs[e];
        int dl = p & (BKT_NODES - 1);
        int pos = beg + atomicAdd(&ofs[dl], 1);
        srcs[pos] = (int)(p >> BKT_SHIFT);
    }
    // ---- folded xs: xs2[node][p] = packed bf16(dinv * x[node][2p..2p+1]) ----
    int base = b * BKT_NODES;
    for (int idx = tid; idx < BKT_NODES * (IN_F / 2); idx += 256) {
        int nl = idx >> 4;
        int p  = idx & 15;
        int nd = base + nl;
        if (nd < n) {
            float2 v = ((const float2*)x)[((size_t)nd << 4) + p];
            float d = sdv[nl];
            unsigned pack = (unsigned)f2bf(v.x * d) | ((unsigned)f2bf(v.y * d) << 16);
            xs2[((size_t)nd << 4) + p] = pack;
        }
    }
}

// ================= fused1: prefetch-pipelined gather -> MLP -> packed bf16 hs2 =================
// 16 nodes/block, 16 lanes/node, lane q handles packed features (2q, 2q+1).
// NEW (R6): srcs for batch k+1 are register-prefetched before gathering batch k —
// overlaps the srcs load latency under the xs2 gather latency, cutting serial memory
// rounds per node from ~4 to ~2.5 (deg~16 = 2 batches). Same traffic, same layout.
__global__ __launch_bounds__(256) void fused1_kernel(
    const int* __restrict__ rowstart, const int* __restrict__ srcs,
    const unsigned* __restrict__ xs2, const float* __restrict__ dinv,
    const float* __restrict__ b1, const float* __restrict__ W1,
    const float* __restrict__ W2, unsigned* __restrict__ hs2p, int n)
{
    __shared__ float W1s[IN_F * HID_F];    // 8 KB  [k*64+j]
    __shared__ float W2s[HID_F * OUT_F];   // 8 KB  [k*32+j]
    __shared__ float grow[16][IN_F + 1];   // padded: bank = (nl+k)%32
    __shared__ float hrow[16][HID_F + 1];  // padded
    int tid = threadIdx.x;
    for (int t = tid; t < IN_F * HID_F; t += 256) W1s[t] = W1[t];
    for (int t = tid; t < HID_F * OUT_F; t += 256) W2s[t] = W2[t];

    int nl = tid >> 4;                 // node-local 0..15
    unsigned q = tid & 15;             // feature-pair index
    int node = blockIdx.x * 16 + nl;
    bool active = node < n;
    int nodec = active ? node : 0;

    int beg = rowstart[nodec], end = active ? rowstart[nodec + 1] : beg;
    unsigned ws = active ? xs2[((unsigned)nodec << 4) + q] : 0u;   // self-loop
    float a0l = bflo(ws), a0h = bfhi(ws);
    float a1l = 0.f, a1h = 0.f, a2l = 0.f, a2h = 0.f, a3l = 0.f, a3h = 0.f;
    float a4l = 0.f, a4h = 0.f, a5l = 0.f, a5h = 0.f, a6l = 0.f, a6h = 0.f;
    float a7l = 0.f, a7h = 0.f;
    int e = beg;

#define GATHER8(s0,s1,s2,s3,s4,s5,s6,s7)                                               \
    {                                                                                   \
        unsigned w0 = xs2[((unsigned)(s0) << 4) + q], w1 = xs2[((unsigned)(s1) << 4) + q]; \
        unsigned w2 = xs2[((unsigned)(s2) << 4) + q], w3 = xs2[((unsigned)(s3) << 4) + q]; \
        unsigned w4 = xs2[((unsigned)(s4) << 4) + q], w5 = xs2[((unsigned)(s5) << 4) + q]; \
        unsigned w6 = xs2[((unsigned)(s6) << 4) + q], w7 = xs2[((unsigned)(s7) << 4) + q]; \
        a0l += bflo(w0); a0h += bfhi(w0); a1l += bflo(w1); a1h += bfhi(w1);             \
        a2l += bflo(w2); a2h += bfhi(w2); a3l += bflo(w3); a3h += bfhi(w3);             \
        a4l += bflo(w4); a4h += bfhi(w4); a5l += bflo(w5); a5h += bfhi(w5);             \
        a6l += bflo(w6); a6h += bfhi(w6); a7l += bflo(w7); a7h += bfhi(w7);             \
    }

    if (e + 8 <= end) {
        int s0 = srcs[e],     s1 = srcs[e + 1], s2 = srcs[e + 2], s3 = srcs[e + 3];
        int s4 = srcs[e + 4], s5 = srcs[e + 5], s6 = srcs[e + 6], s7 = srcs[e + 7];
        for (; e + 16 <= end; e += 8) {
            int t0 = srcs[e + 8],  t1 = srcs[e + 9],  t2 = srcs[e + 10], t3 = srcs[e + 11];
            int t4 = srcs[e + 12], t5 = srcs[e + 13], t6 = srcs[e + 14], t7 = srcs[e + 15];
            GATHER8(s0, s1, s2, s3, s4, s5, s6, s7);
            s0 = t0; s1 = t1; s2 = t2; s3 = t3;
            s4 = t4; s5 = t5; s6 = t6; s7 = t7;
        }
        GATHER8(s0, s1, s2, s3, s4, s5, s6, s7);   // last full batch (no prefetch)
        e += 8;
    }
    for (; e + 4 <= end; e += 4) {
        unsigned o0 = ((unsigned)srcs[e]     << 4) + q, o1 = ((unsigned)srcs[e + 1] << 4) + q;
        unsigned o2 = ((unsigned)srcs[e + 2] << 4) + q, o3 = ((unsigned)srcs[e + 3] << 4) + q;
        unsigned w0 = xs2[o0], w1 = xs2[o1], w2 = xs2[o2], w3 = xs2[o3];
        a0l += bflo(w0); a0h += bfhi(w0); a1l += bflo(w1); a1h += bfhi(w1);
        a2l += bflo(w2); a2h += bfhi(w2); a3l += bflo(w3); a3h += bfhi(w3);
    }
    for (; e < end; ++e) {
        unsigned w0 = xs2[((unsigned)srcs[e] << 4) + q];
        a0l += bflo(w0); a0h += bfhi(w0);
    }
#undef GATHER8

    float dv = dinv[nodec];
    grow[nl][2 * q]     = dv * (((a0l + a1l) + (a2l + a3l)) + ((a4l + a5l) + (a6l + a7l)));
    grow[nl][2 * q + 1] = dv * (((a0h + a1h) + (a2h + a3h)) + ((a4h + a5h) + (a6h + a7h)));
    __syncthreads();

    // ---- MLP: 16 threads/node. hidden features q, q+16, q+32, q+48 ----
    float h0 = b1[q], h1 = b1[q + 16], h2 = b1[q + 32], h3 = b1[q + 48];
    #pragma unroll
    for (int k = 0; k < IN_F; ++k) {
        float gk = grow[nl][k];
        h0 += gk * W1s[k * HID_F + q];
        h1 += gk * W1s[k * HID_F + q + 16];
        h2 += gk * W1s[k * HID_F + q + 32];
        h3 += gk * W1s[k * HID_F + q + 48];
    }
    hrow[nl][q]      = fmaxf(h0, 0.f);
    hrow[nl][q + 16] = fmaxf(h1, 0.f);
    hrow[nl][q + 32] = fmaxf(h2, 0.f);
    hrow[nl][q + 48] = fmaxf(h3, 0.f);
    __syncthreads();

    // ---- W2 matvec: output features 2q, 2q+1; write packed pair ----
    float p0 = 0.f, p1 = 0.f;
    #pragma unroll
    for (int k = 0; k < HID_F; ++k) {
        float hk = hrow[nl][k];
        p0 += hk * W2s[k * OUT_F + 2 * q];
        p1 += hk * W2s[k * OUT_F + 2 * q + 1];
    }
    if (active) {
        unsigned pack = (unsigned)f2bf(dv * p0) | ((unsigned)f2bf(dv * p1) << 16);
        hs2p[((unsigned)node << 4) + q] = pack;
    }
}

// ================= agg2: prefetch-pipelined eighth-wave gather (uint2), finalize =================
// 8 lanes/node, lane r gathers words (2r, 2r+1) via one dwordx2; 8-deep batches with
// register prefetch of next batch's srcs (deg~16 = 2 batches -> ~2.5 serial rounds).
__global__ __launch_bounds__(256) void agg2_kernel(
    const int* __restrict__ rowstart, const int* __restrict__ srcs,
    const uint2* __restrict__ hs2p2, const float* __restrict__ dinv,
    const float* __restrict__ b2, float* __restrict__ out, int n)
{
    int t = blockIdx.x * blockDim.x + threadIdx.x;
    int node = t >> 3;
    if (node >= n) return;
    unsigned r = t & 7;
    int beg = rowstart[node], end = rowstart[node + 1];
    uint2 ws = hs2p2[((unsigned)node << 3) + r];     // self-loop
    float a0x = bflo(ws.x), a0y = bfhi(ws.x), a0z = bflo(ws.y), a0w = bfhi(ws.y);
    float a1x = 0.f, a1y = 0.f, a1z = 0.f, a1w = 0.f;
    float a2x = 0.f, a2y = 0.f, a2z = 0.f, a2w = 0.f;
    float a3x = 0.f, a3y = 0.f, a3z = 0.f, a3w = 0.f;
    int e = beg;

#define GATHER8B(s0,s1,s2,s3,s4,s5,s6,s7)                                              \
    {                                                                                   \
        uint2 w0 = hs2p2[((unsigned)(s0) << 3) + r], w1 = hs2p2[((unsigned)(s1) << 3) + r]; \
        uint2 w2 = hs2p2[((unsigned)(s2) << 3) + r], w3 = hs2p2[((unsigned)(s3) << 3) + r]; \
        uint2 w4 = hs2p2[((unsigned)(s4) << 3) + r], w5 = hs2p2[((unsigned)(s5) << 3) + r]; \
        uint2 w6 = hs2p2[((unsigned)(s6) << 3) + r], w7 = hs2p2[((unsigned)(s7) << 3) + r]; \
        a0x += bflo(w0.x); a0y += bfhi(w0.x); a0z += bflo(w0.y); a0w += bfhi(w0.y);     \
        a1x += bflo(w1.x); a1y += bfhi(w1.x); a1z += bflo(w1.y); a1w += bfhi(w1.y);     \
        a2x += bflo(w2.x); a2y += bfhi(w2.x); a2z += bflo(w2.y); a2w += bfhi(w2.y);     \
        a3x += bflo(w3.x); a3y += bfhi(w3.x); a3z += bflo(w3.y); a3w += bfhi(w3.y);     \
        a0x += bflo(w4.x); a0y += bfhi(w4.x); a0z += bflo(w4.y); a0w += bfhi(w4.y);     \
        a1x += bflo(w5.x); a1y += bfhi(w5.x); a1z += bflo(w5.y); a1w += bfhi(w5.y);     \
        a2x += bflo(w6.x); a2y += bfhi(w6.x); a2z += bflo(w6.y); a2w += bfhi(w6.y);     \
        a3x += bflo(w7.x); a3y += bfhi(w7.x); a3z += bflo(w7.y); a3w += bfhi(w7.y);     \
    }

    if (e + 8 <= end) {
        int s0 = srcs[e],     s1 = srcs[e + 1], s2 = srcs[e + 2], s3 = srcs[e + 3];
        int s4 = srcs[e + 4], s5 = srcs[e + 5], s6 = srcs[e + 6], s7 = srcs[e + 7];
        for (; e + 16 <= end; e += 8) {
            int t0 = srcs[e + 8],  t1 = srcs[e + 9],  t2 = srcs[e + 10], t3 = srcs[e + 11];
            int t4 = srcs[e + 12], t5 = srcs[e + 13], t6 = srcs[e + 14], t7 = srcs[e + 15];
            GATHER8B(s0, s1, s2, s3, s4, s5, s6, s7);
            s0 = t0; s1 = t1; s2 = t2; s3 = t3;
            s4 = t4; s5 = t5; s6 = t6; s7 = t7;
        }
        GATHER8B(s0, s1, s2, s3, s4, s5, s6, s7);
        e += 8;
    }
    for (; e + 4 <= end; e += 4) {
        unsigned o0 = ((unsigned)srcs[e]     << 3) + r, o1 = ((unsigned)srcs[e + 1] << 3) + r;
        unsigned o2 = ((unsigned)srcs[e + 2] << 3) + r, o3 = ((unsigned)srcs[e + 3] << 3) + r;
        uint2 w0 = hs2p2[o0], w1 = hs2p2[o1], w2 = hs2p2[o2], w3 = hs2p2[o3];
        a0x += bflo(w0.x); a0y += bfhi(w0.x); a0z += bflo(w0.y); a0w += bfhi(w0.y);
        a1x += bflo(w1.x); a1y += bfhi(w1.x); a1z += bflo(w1.y); a1w += bfhi(w1.y);
        a2x += bflo(w2.x); a2y += bfhi(w2.x); a2z += bflo(w2.y); a2w += bfhi(w2.y);
        a3x += bflo(w3.x); a3y += bfhi(w3.x); a3z += bflo(w3.y); a3w += bfhi(w3.y);
    }
    for (; e < end; ++e) {
        uint2 w0 = hs2p2[((unsigned)srcs[e] << 3) + r];
        a0x += bflo(w0.x); a0y += bfhi(w0.x); a0z += bflo(w0.y); a0w += bfhi(w0.y);
    }
#undef GATHER8B

    float dvv = dinv[node];
    float4 bb = ((const float4*)b2)[r];
    float4 res;
    res.x = dvv * ((a0x + a1x) + (a2x + a3x)) + bb.x;
    res.y = dvv * ((a0y + a1y) + (a2y + a3y)) + bb.y;
    res.z = dvv * ((a0z + a1z) + (a2z + a3z)) + bb.z;
    res.w = dvv * ((a0w + a1w) + (a2w + a3w)) + bb.w;
    ((float4*)out)[((size_t)node << 3) + r] = res;
}

extern "C" void kernel_launch(void* const* d_in, const int* in_sizes, int n_in,
                              void* d_out, int out_size, void* d_ws, size_t ws_size,
                              hipStream_t stream) {
    const float* x  = (const float*)d_in[0];
    const int*   ei = (const int*)  d_in[1];
    const float* W1 = (const float*)d_in[2];
    const float* b1 = (const float*)d_in[3];
    const float* W2 = (const float*)d_in[4];
    const float* b2 = (const float*)d_in[5];
    float* out = (float*)d_out;

    const int n = in_sizes[0] / IN_F;     // 100000
    const int E = in_sizes[1] / 2;        // 1600000
    const int* src = ei;
    const int* dst = ei + E;

    const int nb = (n + BKT_NODES - 1) >> BKT_SHIFT;   // 391 buckets (<=512)
    const int nc = nb * NBLK;                          // 200192 cells

    // ---- workspace layout: ~27 MB (16 B aligned regions for vector access) ----
    auto align16 = [](int* p) { return (int*)(((uintptr_t)p + 15) & ~(uintptr_t)15); };
    int* ip = (int*)d_ws;
    int* cnt       = ip;                 ip += nc;         // 0.8 MB
    int* cellstart = ip;                 ip += nc + 1;     // 0.8 MB
    int* bsum      = ip;                 ip += nb + 1;
    int* rowstart  = ip;                 ip += n + 1;
    ip = align16(ip);
    unsigned* pairs = (unsigned*)ip;     ip += E;          // 6.4 MB
    int* srcs_srt  = ip;                 ip += E;          // 6.4 MB
    float* dinv = (float*)ip;            ip += n;
    ip = align16(ip);
    unsigned* xs2  = (unsigned*)ip;      ip += (size_t)n * IN_F / 2;   // 6.4 MB
    ip = align16(ip);
    unsigned* hs2p = (unsigned*)ip;                                    // 6.4 MB

    count_kernel<<<NBLK, 256, 0, stream>>>(dst, cnt, E, nb);
    bsum_kernel <<<nb, NBLK, 0, stream>>>(cnt, bsum);
    bscan_kernel<<<1, 512, 0, stream>>>(bsum, nb, cellstart, nc, rowstart, n, E);
    cscan_kernel<<<nb, NBLK, 0, stream>>>(cnt, bsum, cellstart);
    append_kernel<<<NBLK, 256, 0, stream>>>(src, dst, cellstart, pairs, E, nb);
    place_kernel<<<nb, 256, 0, stream>>>(cellstart, pairs, srcs_srt, rowstart, dinv, x, xs2, n);

    fused1_kernel<<<(n + 15) / 16, 256, 0, stream>>>(rowstart, srcs_srt, xs2, dinv, b1, W1, W2, hs2p, n);
    agg2_kernel<<<((size_t)n * 8 + 255) / 256, 256, 0, stream>>>(rowstart, srcs_srt, (const uint2*)hs2p, dinv, b2, out, n);
}